// Round 9
// baseline (1092.053 us; speedup 1.0000x reference)
//
#include <hip/hip_runtime.h>

#define NE 1000000
#define NNODE 100000

typedef __attribute__((ext_vector_type(8))) _Float16 half8;
typedef __attribute__((ext_vector_type(4))) float f32x4;

// ---------------- ws layout (in _Float16 elements) ----------------
// [0,      8192)   W_efeat  f16  [128][64]   (row-major, linear)
// [8192,  16384)   W_src    f16
// [16384, 24576)   W_dst    f16
// [24576, 40960)   W_out    f16  [128][128]  (row-major, linear)
// [40960, +NN*128) P_src    f16  [100000][128]
// [ ... , +NN*128) P_dst    f16  (includes b1)

// ---------------- kernel A: convert weights to f16 ----------------
__global__ void k_convw(const float* __restrict__ Wef, const float* __restrict__ Wsrc,
                        const float* __restrict__ Wdst, const float* __restrict__ Wout,
                        _Float16* __restrict__ wsh) {
    int i = blockIdx.x * 256 + threadIdx.x;
    if (i < 8192)        wsh[i] = (_Float16)Wef[i];
    else if (i < 16384)  wsh[i] = (_Float16)Wsrc[i - 8192];
    else if (i < 24576)  wsh[i] = (_Float16)Wdst[i - 16384];
    else if (i < 40960)  wsh[i] = (_Float16)Wout[i - 24576];
}

// ---------------- kernel B: node projections -> P tables ----------------
__global__ __launch_bounds__(256) void k_nodeproj(
    const float* __restrict__ src_feat, const float* __restrict__ dst_feat,
    const _Float16* __restrict__ Wsrc16, const _Float16* __restrict__ Wdst16,
    const float* __restrict__ b1,
    _Float16* __restrict__ Psrc, _Float16* __restrict__ Pdst)
{
    const int t = threadIdx.x;
    const bool isDst = (blockIdx.y != 0);
    const float* feat = isDst ? dst_feat : src_feat;
    const _Float16* W = isDst ? Wdst16 : Wsrc16;
    _Float16* P = isDst ? Pdst : Psrc;
    const int base = blockIdx.x * 64;

    __shared__ _Float16 sH[64 * 128];   // XOR-swizzled

    const int lane = t & 63, wid = t >> 6, l15 = lane & 15, g = lane >> 4;
    const int rb = wid * 16;
    int fr = base + rb + l15; if (fr >= NNODE) fr = NNODE - 1;

    f32x4 acc[8];
#pragma unroll
    for (int nt = 0; nt < 8; ++nt) acc[nt] = {0.f, 0.f, 0.f, 0.f};
#pragma unroll
    for (int ks = 0; ks < 2; ++ks) {
        const float* ap = &feat[(size_t)fr * 64 + ks * 32 + g * 8];
        float4 v0 = *reinterpret_cast<const float4*>(ap);
        float4 v1 = *reinterpret_cast<const float4*>(ap + 4);
        half8 a = { (_Float16)v0.x, (_Float16)v0.y, (_Float16)v0.z, (_Float16)v0.w,
                    (_Float16)v1.x, (_Float16)v1.y, (_Float16)v1.z, (_Float16)v1.w };
        int kb = ks * 4 + g;
#pragma unroll
        for (int nt = 0; nt < 8; ++nt) {
            int row = nt * 16 + l15;
            half8 b = *reinterpret_cast<const half8*>(&W[row * 64 + kb * 8]);
            acc[nt] = __builtin_amdgcn_mfma_f32_16x16x32_f16(a, b, acc[nt], 0, 0, 0);
        }
    }
    // scatter D (col = l15, row = 4g+r) into sH (wave-private rows [rb, rb+16))
#pragma unroll
    for (int nt = 0; nt < 8; ++nt) {
#pragma unroll
        for (int r = 0; r < 4; ++r) {
            int row = rb + g * 4 + r;
            int col = nt * 16 + l15;
            int k8 = col >> 3, e = col & 7;
            sH[row * 128 + ((k8 ^ (row & 7)) << 3) + e] = (_Float16)acc[nt][r];
        }
    }
    __syncthreads();   // copy-out below is cross-wave

    // coalesced copy-out (+bias for dst)
    {
        int r2 = t >> 2, q2 = t & 3;
        int orow = base + r2;
        if (orow < NNODE) {
#pragma unroll
            for (int i = 0; i < 4; ++i) {
                int k8 = q2 * 4 + i;
                half8 h = *reinterpret_cast<const half8*>(&sH[r2 * 128 + ((k8 ^ (r2 & 7)) << 3)]);
                if (isDst) {
#pragma unroll
                    for (int j = 0; j < 8; ++j)
                        h[j] = (_Float16)((float)h[j] + b1[k8 * 8 + j]);
                }
                *reinterpret_cast<half8*>(&P[(size_t)orow * 128 + k8 * 8]) = h;
            }
        }
    }
}

// ---------------- kernel C: edge MLP + gather + silu + LN ----------------
// 64 edges / block, 256 threads (4 waves, 16 rows each). sH is wave-private
// (wave w touches only rows [16w,16w+16)) -> NO barriers anywhere.
// Weights read directly from global (L1/L2-resident, same lines for all blocks).
// launch_bounds (256,4): VGPR cap 128 -> keeps the 8-deep B-frag load pipeline
// and the held gather prefetch (the (256,5)/48-VGPR cap serialized everything).
__global__ __launch_bounds__(256, 4) void k_edge(
    const float* __restrict__ efeat,
    const int* __restrict__ src_idx, const int* __restrict__ dst_idx,
    const _Float16* __restrict__ W1g, const _Float16* __restrict__ W2g,
    const _Float16* __restrict__ Psrc, const _Float16* __restrict__ Pdst,
    const float* __restrict__ b_out, const float* __restrict__ gamma_,
    const float* __restrict__ beta_, float* __restrict__ out)
{
    __shared__ _Float16 sH[64 * 128];   // 16 KB, XOR-swizzled, wave-private rows

    const int t = threadIdx.x;
    const size_t base = (size_t)blockIdx.x * 64;
    const int lane = t & 63, wid = t >> 6, l15 = lane & 15, g = lane >> 4;
    const int rb = wid * 16;
    const int r2 = t >> 2, q2 = t & 3;     // r2 in [16*wid, 16*wid+16) -> wave-local

    // ---- issue gathers early (hide LLC latency under layer-1 work) ----
    size_t eidx = base + r2; if (eidx >= NE) eidx = NE - 1;
    int si = src_idx[eidx];
    int di = dst_idx[eidx];
    uint4 ps[4], pd[4];
    {
        const uint4* Ps4 = reinterpret_cast<const uint4*>(Psrc + (size_t)si * 128);
        const uint4* Pd4 = reinterpret_cast<const uint4*>(Pdst + (size_t)di * 128);
#pragma unroll
        for (int i = 0; i < 4; ++i) { ps[i] = Ps4[q2 * 4 + i]; pd[i] = Pd4[q2 * 4 + i]; }
    }

    // ---- layer 1: h1 = efeat @ Wef^T (A from global f32->f16, B from global f16) ----
    size_t er = base + rb + l15; if (er >= NE) er = NE - 1;
    f32x4 acc[8];
#pragma unroll
    for (int nt = 0; nt < 8; ++nt) acc[nt] = {0.f, 0.f, 0.f, 0.f};
#pragma unroll
    for (int ks = 0; ks < 2; ++ks) {
        const float* ap = &efeat[er * 64 + ks * 32 + g * 8];
        float4 v0 = *reinterpret_cast<const float4*>(ap);
        float4 v1 = *reinterpret_cast<const float4*>(ap + 4);
        half8 a = { (_Float16)v0.x, (_Float16)v0.y, (_Float16)v0.z, (_Float16)v0.w,
                    (_Float16)v1.x, (_Float16)v1.y, (_Float16)v1.z, (_Float16)v1.w };
        int kb = ks * 4 + g;
#pragma unroll
        for (int nt = 0; nt < 8; ++nt) {
            int row = nt * 16 + l15;
            half8 b = *reinterpret_cast<const half8*>(&W1g[row * 64 + kb * 8]);
            acc[nt] = __builtin_amdgcn_mfma_f32_16x16x32_f16(a, b, acc[nt], 0, 0, 0);
        }
    }
    // scatter h1 -> sH (wave-private rows; compiler orders via lgkmcnt)
#pragma unroll
    for (int nt = 0; nt < 8; ++nt) {
#pragma unroll
        for (int r = 0; r < 4; ++r) {
            int row = rb + g * 4 + r;
            int col = nt * 16 + l15;
            int k8 = col >> 3, e = col & 7;
            sH[row * 128 + ((k8 ^ (row & 7)) << 3) + e] = (_Float16)acc[nt][r];
        }
    }

    // ---- phase 2: h = silu(h1 + P_src[si] + P_dst[di])  (wave-local rows) ----
#pragma unroll
    for (int i = 0; i < 4; ++i) {
        int k8 = q2 * 4 + i;
        _Float16* hp = &sH[r2 * 128 + ((k8 ^ (r2 & 7)) << 3)];
        half8 h = *reinterpret_cast<const half8*>(hp);
        half8 a = __builtin_bit_cast(half8, ps[i]);
        half8 b = __builtin_bit_cast(half8, pd[i]);
#pragma unroll
        for (int j = 0; j < 8; ++j) {
            float x = (float)h[j] + (float)a[j] + (float)b[j];
            float sg = __builtin_amdgcn_rcpf(1.0f + __expf(-x));
            h[j] = (_Float16)(x * sg);
        }
        *reinterpret_cast<half8*>(hp) = h;
    }

    // ---- layer 2: y = h @ Wout^T (A from sH wave-local, B from global) ----
    f32x4 acc2[8];
#pragma unroll
    for (int nt = 0; nt < 8; ++nt) acc2[nt] = {0.f, 0.f, 0.f, 0.f};
#pragma unroll
    for (int ks = 0; ks < 4; ++ks) {
        int row_a = rb + l15;
        int kb = ks * 4 + g;
        half8 a = *reinterpret_cast<const half8*>(&sH[row_a * 128 + ((kb ^ (row_a & 7)) << 3)]);
#pragma unroll
        for (int nt = 0; nt < 8; ++nt) {
            int row = nt * 16 + l15;
            half8 b = *reinterpret_cast<const half8*>(&W2g[row * 128 + kb * 8]);
            acc2[nt] = __builtin_amdgcn_mfma_f32_16x16x32_f16(a, b, acc2[nt], 0, 0, 0);
        }
    }

    // ---- bias + LayerNorm (16-lane shuffle reductions, wave-local) ----
    float ga[8], be[8];
#pragma unroll
    for (int nt = 0; nt < 8; ++nt) {
        int col = nt * 16 + l15;
        float bo = b_out[col];
        ga[nt] = gamma_[col]; be[nt] = beta_[col];
#pragma unroll
        for (int r = 0; r < 4; ++r) acc2[nt][r] += bo;
    }
#pragma unroll
    for (int r = 0; r < 4; ++r) {
        float s = 0.f, sq = 0.f;
#pragma unroll
        for (int nt = 0; nt < 8; ++nt) { float x = acc2[nt][r]; s += x; sq += x * x; }
#pragma unroll
        for (int m = 1; m <= 8; m <<= 1) {
            s  += __shfl_xor(s,  m, 64);
            sq += __shfl_xor(sq, m, 64);
        }
        float mean = s * 0.0078125f;                 // /128
        float var  = sq * 0.0078125f - mean * mean;
        float rstd = __builtin_amdgcn_rsqf(var + 1e-5f);
        size_t row = base + rb + g * 4 + r;
        if (row < NE) {
            float* op = &out[row * 128 + l15];
#pragma unroll
            for (int nt = 0; nt < 8; ++nt) {
                op[nt * 16] = (acc2[nt][r] - mean) * rstd * ga[nt] + be[nt];
            }
        }
    }
}

extern "C" void kernel_launch(void* const* d_in, const int* in_sizes, int n_in,
                              void* d_out, int out_size, void* d_ws, size_t ws_size,
                              hipStream_t stream) {
    const float* efeat    = (const float*)d_in[0];
    const float* src_feat = (const float*)d_in[1];
    const float* dst_feat = (const float*)d_in[2];
    const int*   src_idx  = (const int*)d_in[3];
    const int*   dst_idx  = (const int*)d_in[4];
    const float* W_efeat  = (const float*)d_in[5];
    const float* W_src    = (const float*)d_in[6];
    const float* W_dst    = (const float*)d_in[7];
    const float* b1       = (const float*)d_in[8];
    const float* W_out    = (const float*)d_in[9];
    const float* b_out    = (const float*)d_in[10];
    const float* ln_g     = (const float*)d_in[11];
    const float* ln_b     = (const float*)d_in[12];
    float* out = (float*)d_out;

    _Float16* wsh   = reinterpret_cast<_Float16*>(d_ws);
    _Float16* wWef  = wsh;
    _Float16* wWsrc = wsh + 8192;
    _Float16* wWdst = wsh + 16384;
    _Float16* wWout = wsh + 24576;
    _Float16* Psrc  = wsh + 40960;
    _Float16* Pdst  = Psrc + (size_t)NNODE * 128;

    k_convw<<<160, 256, 0, stream>>>(W_efeat, W_src, W_dst, W_out, wsh);
    dim3 gB(1563, 2);
    k_nodeproj<<<gB, 256, 0, stream>>>(src_feat, dst_feat, wWsrc, wWdst, b1, Psrc, Pdst);
    k_edge<<<15625, 256, 0, stream>>>(efeat, src_idx, dst_idx, wWef, wWout,
                                      Psrc, Pdst, b_out, ln_g, ln_b, out);
}

// Round 10
// 826.137 us; speedup vs baseline: 1.3219x; 1.3219x over previous
//
#include <hip/hip_runtime.h>

#define NE 1000000
#define NNODE 100000

typedef __attribute__((ext_vector_type(8))) _Float16 half8;
typedef __attribute__((ext_vector_type(4))) float f32x4;

// ---------------- ws layout (in _Float16 elements) ----------------
// [0,      8192)   W_efeat  f16  [128][64]   (row-major, linear)
// [8192,  16384)   W_src    f16
// [16384, 24576)   W_dst    f16
// [24576, 40960)   W_out    f16  [128][128]  (row-major, linear)
// [40960, +NN*128) P_src    f16  [100000][128]
// [ ... , +NN*128) P_dst    f16  (includes b1)

// ---------------- kernel A: convert weights to f16 ----------------
__global__ void k_convw(const float* __restrict__ Wef, const float* __restrict__ Wsrc,
                        const float* __restrict__ Wdst, const float* __restrict__ Wout,
                        _Float16* __restrict__ wsh) {
    int i = blockIdx.x * 256 + threadIdx.x;
    if (i < 8192)        wsh[i] = (_Float16)Wef[i];
    else if (i < 16384)  wsh[i] = (_Float16)Wsrc[i - 8192];
    else if (i < 24576)  wsh[i] = (_Float16)Wdst[i - 16384];
    else if (i < 40960)  wsh[i] = (_Float16)Wout[i - 24576];
}

// ---------------- kernel B: node projections -> P tables ----------------
__global__ __launch_bounds__(256) void k_nodeproj(
    const float* __restrict__ src_feat, const float* __restrict__ dst_feat,
    const _Float16* __restrict__ Wsrc16, const _Float16* __restrict__ Wdst16,
    const float* __restrict__ b1,
    _Float16* __restrict__ Psrc, _Float16* __restrict__ Pdst)
{
    const int t = threadIdx.x;
    const bool isDst = (blockIdx.y != 0);
    const float* feat = isDst ? dst_feat : src_feat;
    const _Float16* W = isDst ? Wdst16 : Wsrc16;
    _Float16* P = isDst ? Pdst : Psrc;
    const int base = blockIdx.x * 64;

    __shared__ _Float16 sH[64 * 128];   // XOR-swizzled

    const int lane = t & 63, wid = t >> 6, l15 = lane & 15, g = lane >> 4;
    const int rb = wid * 16;
    int fr = base + rb + l15; if (fr >= NNODE) fr = NNODE - 1;

    f32x4 acc[8];
#pragma unroll
    for (int nt = 0; nt < 8; ++nt) acc[nt] = {0.f, 0.f, 0.f, 0.f};
#pragma unroll
    for (int ks = 0; ks < 2; ++ks) {
        const float* ap = &feat[(size_t)fr * 64 + ks * 32 + g * 8];
        float4 v0 = *reinterpret_cast<const float4*>(ap);
        float4 v1 = *reinterpret_cast<const float4*>(ap + 4);
        half8 a = { (_Float16)v0.x, (_Float16)v0.y, (_Float16)v0.z, (_Float16)v0.w,
                    (_Float16)v1.x, (_Float16)v1.y, (_Float16)v1.z, (_Float16)v1.w };
        int kb = ks * 4 + g;
#pragma unroll
        for (int nt = 0; nt < 8; ++nt) {
            int row = nt * 16 + l15;
            half8 b = *reinterpret_cast<const half8*>(&W[row * 64 + kb * 8]);
            acc[nt] = __builtin_amdgcn_mfma_f32_16x16x32_f16(a, b, acc[nt], 0, 0, 0);
        }
    }
    // scatter D (col = l15, row = 4g+r) into sH (wave-private rows [rb, rb+16))
#pragma unroll
    for (int nt = 0; nt < 8; ++nt) {
#pragma unroll
        for (int r = 0; r < 4; ++r) {
            int row = rb + g * 4 + r;
            int col = nt * 16 + l15;
            int k8 = col >> 3, e = col & 7;
            sH[row * 128 + ((k8 ^ (row & 7)) << 3) + e] = (_Float16)acc[nt][r];
        }
    }
    __syncthreads();   // copy-out below is cross-wave

    // coalesced copy-out (+bias for dst)
    {
        int r2 = t >> 2, q2 = t & 3;
        int orow = base + r2;
        if (orow < NNODE) {
#pragma unroll
            for (int i = 0; i < 4; ++i) {
                int k8 = q2 * 4 + i;
                half8 h = *reinterpret_cast<const half8*>(&sH[r2 * 128 + ((k8 ^ (r2 & 7)) << 3)]);
                if (isDst) {
#pragma unroll
                    for (int j = 0; j < 8; ++j)
                        h[j] = (_Float16)((float)h[j] + b1[k8 * 8 + j]);
                }
                *reinterpret_cast<half8*>(&P[(size_t)orow * 128 + k8 * 8]) = h;
            }
        }
    }
}

// ---------------- kernel C: edge MLP + gather + silu + LN ----------------
// 128 edges / block, 512 threads (8 waves, 16 rows each).
// Weights staged in LDS (fast ds_read_b128 MFMA operands — round 4's proven
// per-wave path), amortized over 128 edges. sH wave-private -> single barrier
// (after weight staging). Direct-from-reg LN store (no sLN overlay).
// LDS = 16+32+32 = 80 KB -> 2 blocks/CU = 16 waves/CU (round 8's occupancy).
__global__ __launch_bounds__(512, 4) void k_edge(
    const float* __restrict__ efeat,
    const int* __restrict__ src_idx, const int* __restrict__ dst_idx,
    const _Float16* __restrict__ W1g, const _Float16* __restrict__ W2g,
    const _Float16* __restrict__ Psrc, const _Float16* __restrict__ Pdst,
    const float* __restrict__ b_out, const float* __restrict__ gamma_,
    const float* __restrict__ beta_, float* __restrict__ out)
{
    __shared__ _Float16 sW1[128 * 64];    // 16 KB, XOR-swizzled
    __shared__ _Float16 sW2[128 * 128];   // 32 KB, XOR-swizzled
    __shared__ _Float16 sH [128 * 128];   // 32 KB, XOR-swizzled, wave-private rows

    const int t = threadIdx.x;                 // 0..511
    const size_t base = (size_t)blockIdx.x * 128;
    const int lane = t & 63, wid = t >> 6;     // wid 0..7
    const int l15 = lane & 15, g = lane >> 4;
    const int rb = wid * 16;                   // wave's edge-row stripe
    const int r2 = t >> 2, q2 = t & 3;         // r2 0..127, wave-local (r2 in [16w,16w+16))

    // ---- issue gathers early (hide LLC latency under staging + layer 1) ----
    size_t eidx = base + r2; if (eidx >= NE) eidx = NE - 1;
    int si = src_idx[eidx];
    int di = dst_idx[eidx];
    uint4 ps[4], pd[4];
    {
        const uint4* Ps4 = reinterpret_cast<const uint4*>(Psrc + (size_t)si * 128);
        const uint4* Pd4 = reinterpret_cast<const uint4*>(Pdst + (size_t)di * 128);
#pragma unroll
        for (int i = 0; i < 4; ++i) { ps[i] = Ps4[q2 * 4 + i]; pd[i] = Pd4[q2 * 4 + i]; }
    }

    // ---- stage W1 (1024 chunks / 2 iters), W2 (2048 chunks / 4 iters) ----
#pragma unroll
    for (int it = 0; it < 2; ++it) {
        int c = it * 512 + t;
        int row = c >> 3, k8 = c & 7;
        *reinterpret_cast<uint4*>(&sW1[row * 64 + ((k8 ^ (row & 7)) << 3)]) =
            reinterpret_cast<const uint4*>(W1g)[c];
    }
#pragma unroll
    for (int it = 0; it < 4; ++it) {
        int c = it * 512 + t;
        int row = c >> 4, k8 = c & 15;
        *reinterpret_cast<uint4*>(&sW2[row * 128 + ((k8 ^ (row & 7)) << 3)]) =
            reinterpret_cast<const uint4*>(W2g)[c];
    }
    __syncthreads();   // the ONLY barrier

    // ---- layer 1: h1 = efeat @ Wef^T (A from global f32->f16, B from sW1) ----
    size_t er = base + rb + l15; if (er >= NE) er = NE - 1;
    f32x4 acc[8];
#pragma unroll
    for (int nt = 0; nt < 8; ++nt) acc[nt] = {0.f, 0.f, 0.f, 0.f};
#pragma unroll
    for (int ks = 0; ks < 2; ++ks) {
        const float* ap = &efeat[er * 64 + ks * 32 + g * 8];
        float4 v0 = *reinterpret_cast<const float4*>(ap);
        float4 v1 = *reinterpret_cast<const float4*>(ap + 4);
        half8 a = { (_Float16)v0.x, (_Float16)v0.y, (_Float16)v0.z, (_Float16)v0.w,
                    (_Float16)v1.x, (_Float16)v1.y, (_Float16)v1.z, (_Float16)v1.w };
        int kb = ks * 4 + g;
#pragma unroll
        for (int nt = 0; nt < 8; ++nt) {
            int row = nt * 16 + l15;
            half8 b = *reinterpret_cast<const half8*>(&sW1[row * 64 + ((kb ^ (row & 7)) << 3)]);
            acc[nt] = __builtin_amdgcn_mfma_f32_16x16x32_f16(a, b, acc[nt], 0, 0, 0);
        }
    }
    // scatter h1 -> sH (wave-private rows; same-wave ordering via lgkmcnt)
#pragma unroll
    for (int nt = 0; nt < 8; ++nt) {
#pragma unroll
        for (int r = 0; r < 4; ++r) {
            int row = rb + g * 4 + r;
            int col = nt * 16 + l15;
            int k8 = col >> 3, e = col & 7;
            sH[row * 128 + ((k8 ^ (row & 7)) << 3) + e] = (_Float16)acc[nt][r];
        }
    }

    // ---- phase 2: h = silu(h1 + P_src[si] + P_dst[di])  (wave-local rows) ----
#pragma unroll
    for (int i = 0; i < 4; ++i) {
        int k8 = q2 * 4 + i;
        _Float16* hp = &sH[r2 * 128 + ((k8 ^ (r2 & 7)) << 3)];
        half8 h = *reinterpret_cast<const half8*>(hp);
        half8 a = __builtin_bit_cast(half8, ps[i]);
        half8 b = __builtin_bit_cast(half8, pd[i]);
#pragma unroll
        for (int j = 0; j < 8; ++j) {
            float x = (float)h[j] + (float)a[j] + (float)b[j];
            float sg = __builtin_amdgcn_rcpf(1.0f + __expf(-x));
            h[j] = (_Float16)(x * sg);
        }
        *reinterpret_cast<half8*>(hp) = h;
    }

    // ---- layer 2: y = h @ Wout^T (A from sH wave-local, B from sW2) ----
    f32x4 acc2[8];
#pragma unroll
    for (int nt = 0; nt < 8; ++nt) acc2[nt] = {0.f, 0.f, 0.f, 0.f};
#pragma unroll
    for (int ks = 0; ks < 4; ++ks) {
        int row_a = rb + l15;
        int kb = ks * 4 + g;
        half8 a = *reinterpret_cast<const half8*>(&sH[row_a * 128 + ((kb ^ (row_a & 7)) << 3)]);
#pragma unroll
        for (int nt = 0; nt < 8; ++nt) {
            int row = nt * 16 + l15;
            half8 b = *reinterpret_cast<const half8*>(&sW2[row * 128 + ((kb ^ (row & 7)) << 3)]);
            acc2[nt] = __builtin_amdgcn_mfma_f32_16x16x32_f16(a, b, acc2[nt], 0, 0, 0);
        }
    }

    // ---- bias + LayerNorm (16-lane shuffle reductions, wave-local) ----
    float ga[8], be[8];
#pragma unroll
    for (int nt = 0; nt < 8; ++nt) {
        int col = nt * 16 + l15;
        float bo = b_out[col];
        ga[nt] = gamma_[col]; be[nt] = beta_[col];
#pragma unroll
        for (int r = 0; r < 4; ++r) acc2[nt][r] += bo;
    }
#pragma unroll
    for (int r = 0; r < 4; ++r) {
        float s = 0.f, sq = 0.f;
#pragma unroll
        for (int nt = 0; nt < 8; ++nt) { float x = acc2[nt][r]; s += x; sq += x * x; }
#pragma unroll
        for (int m = 1; m <= 8; m <<= 1) {
            s  += __shfl_xor(s,  m, 64);
            sq += __shfl_xor(sq, m, 64);
        }
        float mean = s * 0.0078125f;                 // /128
        float var  = sq * 0.0078125f - mean * mean;
        float rstd = __builtin_amdgcn_rsqf(var + 1e-5f);
        size_t row = base + rb + g * 4 + r;
        if (row < NE) {
            float* op = &out[row * 128 + l15];
#pragma unroll
            for (int nt = 0; nt < 8; ++nt) {
                op[nt * 16] = (acc2[nt][r] - mean) * rstd * ga[nt] + be[nt];
            }
        }
    }
}

extern "C" void kernel_launch(void* const* d_in, const int* in_sizes, int n_in,
                              void* d_out, int out_size, void* d_ws, size_t ws_size,
                              hipStream_t stream) {
    const float* efeat    = (const float*)d_in[0];
    const float* src_feat = (const float*)d_in[1];
    const float* dst_feat = (const float*)d_in[2];
    const int*   src_idx  = (const int*)d_in[3];
    const int*   dst_idx  = (const int*)d_in[4];
    const float* W_efeat  = (const float*)d_in[5];
    const float* W_src    = (const float*)d_in[6];
    const float* W_dst    = (const float*)d_in[7];
    const float* b1       = (const float*)d_in[8];
    const float* W_out    = (const float*)d_in[9];
    const float* b_out    = (const float*)d_in[10];
    const float* ln_g     = (const float*)d_in[11];
    const float* ln_b     = (const float*)d_in[12];
    float* out = (float*)d_out;

    _Float16* wsh   = reinterpret_cast<_Float16*>(d_ws);
    _Float16* wWef  = wsh;
    _Float16* wWsrc = wsh + 8192;
    _Float16* wWdst = wsh + 16384;
    _Float16* wWout = wsh + 24576;
    _Float16* Psrc  = wsh + 40960;
    _Float16* Pdst  = Psrc + (size_t)NNODE * 128;

    k_convw<<<160, 256, 0, stream>>>(W_efeat, W_src, W_dst, W_out, wsh);
    dim3 gB(1563, 2);
    k_nodeproj<<<gB, 256, 0, stream>>>(src_feat, dst_feat, wWsrc, wWdst, b1, Psrc, Pdst);
    k_edge<<<7813, 512, 0, stream>>>(efeat, src_idx, dst_idx, wWef, wWout,
                                     Psrc, Pdst, b_out, ln_g, ln_b, out);
}